// Round 12
// baseline (127.845 us; speedup 1.0000x reference)
//
#include <hip/hip_runtime.h>
#include <hip/hip_fp16.h>

// CapsNet dynamic routing, FULLY FUSED — no intermediate in global memory.
// x: [128, 1152, 8] fp32, w: [1152, 10, 8, 16] fp32 -> v: [128, 10, 16] fp32
// R11 measurement: two-phase floor is the 47MB u_hat round-trip itself
// (route replay on warm L3 = 18.9us = 2.5 TB/s; p1 = 20.5us). Eliminate it.
// Block = 384 thr x (one j, TWO b's): each thread builds u_hat[2 pairs][3 i][16 m]
// from x,w directly (one w-row read serves both pairs), holds it packed __half2
// in 48 VGPRs, then runs the R4-proven DPP+LDS routing core per pair.

#define NB 128
#define NI 1152
#define NJ 10
#define ID 8
#define OD 16
#define NTH 384          // 6 waves
#define KPT 3            // i-rows per thread: 1152 / 384
#define NW (NTH / 64)

// ---- DPP wave-64 sum (rocPRIM pattern): full sum lands in lane 63 ----
template<int ctrl, int rmask, int bmask>
__device__ __forceinline__ float dpp_add(float x) {
    int y = __builtin_amdgcn_update_dpp(0, __builtin_bit_cast(int, x),
                                        ctrl, rmask, bmask, false);
    return x + __builtin_bit_cast(float, y);
}
__device__ __forceinline__ float wave_sum63(float x) {
    x = dpp_add<0x111, 0xf, 0xf>(x);  // row_shr:1
    x = dpp_add<0x112, 0xf, 0xf>(x);  // row_shr:2
    x = dpp_add<0x114, 0xf, 0xe>(x);  // row_shr:4
    x = dpp_add<0x118, 0xf, 0xc>(x);  // row_shr:8
    x = dpp_add<0x142, 0xa, 0xf>(x);  // row_bcast:15
    x = dpp_add<0x143, 0xc, 0xf>(x);  // row_bcast:31
    return x;                          // lane 63 = sum of all 64 lanes
}

__global__ __launch_bounds__(NTH) void caps_fused_kernel(
    const float* __restrict__ x, const float* __restrict__ w,
    float* __restrict__ out)
{
    const int t  = threadIdx.x;
    const int j  = blockIdx.x >> 6;        // 0..9  (j-major dispatch)
    const int bq = blockIdx.x & 63;        // 0..63
    const int b0 = bq * 2;

    // ---------------- Build u_hat for 2 pairs, 3 i-rows each ----------------
    // Per (k): w row [128 floats] streamed as 8n x 4xfloat4 bursts (each lane's
    // 512B row read linearly -> sectors fetched once, consumed immediately).
    __half2 uh[2][KPT][8];
    #pragma unroll
    for (int k = 0; k < KPT; ++k) {
        const int i = t + k * NTH;
        const float* wp = w + ((size_t)i * NJ + j) * (ID * OD);

        float xp[2][ID];
        #pragma unroll
        for (int p = 0; p < 2; ++p) {
            const float* xr = x + ((size_t)(b0 + p) * NI + i) * ID;
            *(float4*)&xp[p][0] = *(const float4*)(xr);
            *(float4*)&xp[p][4] = *(const float4*)(xr + 4);
        }

        float acc[2][OD];
        #pragma unroll
        for (int p = 0; p < 2; ++p)
            #pragma unroll
            for (int m = 0; m < OD; ++m) acc[p][m] = 0.0f;

        #pragma unroll
        for (int n = 0; n < ID; ++n) {
            float wr[OD];
            *(float4*)(wr + 0)  = *(const float4*)(wp + n * OD + 0);
            *(float4*)(wr + 4)  = *(const float4*)(wp + n * OD + 4);
            *(float4*)(wr + 8)  = *(const float4*)(wp + n * OD + 8);
            *(float4*)(wr + 12) = *(const float4*)(wp + n * OD + 12);
            #pragma unroll
            for (int p = 0; p < 2; ++p) {
                const float xn = xp[p][n];
                #pragma unroll
                for (int m = 0; m < OD; ++m)
                    acc[p][m] = fmaf(xn, wr[m], acc[p][m]);
            }
        }
        #pragma unroll
        for (int p = 0; p < 2; ++p)
            #pragma unroll
            for (int q = 0; q < 8; ++q)
                uh[p][k][q] = __floats2half2_rn(acc[p][2*q], acc[p][2*q+1]);
    }

    // ---------------- Route each pair (R4-proven core, u packed) ----------------
    __shared__ float4 red4[NW][5];
    const int wavei = t >> 6;
    const int lane  = t & 63;

    #pragma unroll 1
    for (int p = 0; p < 2; ++p) {
        __syncthreads();   // red4 safe between pairs

        float logit[KPT] = {0.0f, 0.0f, 0.0f};
        float v[OD];

        #pragma unroll 1
        for (int iter = 0; iter < 3; ++iter) {
            float acc[OD + 1];
            #pragma unroll
            for (int q = 0; q <= OD; ++q) acc[q] = 0.0f;
            #pragma unroll
            for (int k = 0; k < KPT; ++k) {
                const float c = __expf(logit[k]);   // iter 0: exp(0)=1 exactly
                acc[OD] += c;
                #pragma unroll
                for (int q = 0; q < 8; ++q) {
                    acc[2*q]   = fmaf(c, __low2float(uh[p][k][q]),  acc[2*q]);
                    acc[2*q+1] = fmaf(c, __high2float(uh[p][k][q]), acc[2*q+1]);
                }
            }
            #pragma unroll
            for (int q = 0; q <= OD; ++q) acc[q] = wave_sum63(acc[q]);

            if (iter != 0) __syncthreads();
            if (lane == 63) {
                red4[wavei][0] = make_float4(acc[0],  acc[1],  acc[2],  acc[3]);
                red4[wavei][1] = make_float4(acc[4],  acc[5],  acc[6],  acc[7]);
                red4[wavei][2] = make_float4(acc[8],  acc[9],  acc[10], acc[11]);
                red4[wavei][3] = make_float4(acc[12], acc[13], acc[14], acc[15]);
                red4[wavei][4] = make_float4(acc[16], 0.f, 0.f, 0.f);
            }
            __syncthreads();

            float tot[OD + 1];
            #pragma unroll
            for (int g = 0; g < 5; ++g) {
                float4 sum = red4[0][g];
                #pragma unroll
                for (int wv = 1; wv < NW; ++wv) {
                    float4 r = red4[wv][g];
                    sum.x += r.x; sum.y += r.y; sum.z += r.z; sum.w += r.w;
                }
                if (g < 4) {
                    tot[4*g+0] = sum.x; tot[4*g+1] = sum.y;
                    tot[4*g+2] = sum.z; tot[4*g+3] = sum.w;
                } else {
                    tot[OD] = sum.x;
                }
            }

            const float inv_den = 1.0f / tot[OD];
            float s2 = 0.0f;
            float sv[OD];
            #pragma unroll
            for (int m = 0; m < OD; ++m) {
                sv[m] = tot[m] * inv_den;
                s2 = fmaf(sv[m], sv[m], s2);
            }
            const float scale = (s2 / (1.0f + s2)) / sqrtf(s2 + 1e-8f);
            #pragma unroll
            for (int m = 0; m < OD; ++m) v[m] = scale * sv[m];

            if (iter < 2) {
                #pragma unroll
                for (int k = 0; k < KPT; ++k) {
                    float a = 0.0f;
                    #pragma unroll
                    for (int q = 0; q < 8; ++q) {
                        a = fmaf(v[2*q],   __low2float(uh[p][k][q]),  a);
                        a = fmaf(v[2*q+1], __high2float(uh[p][k][q]), a);
                    }
                    logit[k] += a;
                }
            }
        }

        if (t < OD) out[((size_t)(b0 + p) * NJ + j) * OD + t] = v[t];
    }
}

extern "C" void kernel_launch(void* const* d_in, const int* in_sizes, int n_in,
                              void* d_out, int out_size, void* d_ws, size_t ws_size,
                              hipStream_t stream) {
    const float* x = (const float*)d_in[2];
    const float* w = (const float*)d_in[3];
    float* out = (float*)d_out;
    // grid: j-major, 64 b-pair blocks per j -> 640 blocks
    hipLaunchKernelGGL(caps_fused_kernel, dim3(NJ * 64), dim3(NTH), 0, stream,
                       x, w, out);
}